// Round 1
// baseline (297.939 us; speedup 1.0000x reference)
//
#include <hip/hip_runtime.h>

// out[b, i, j] = x[b, i, i+j] if i+j < L else 0
// B=4, L=4096, LIMIT=256. Pure memory-bound band gather.
// One thread per float4 of output: 4 predicated scalar loads (band start is
// only 4B-aligned; tail rows of the last batch would read OOB, so predicate
// rather than clamp), one aligned float4 store.

constexpr int B_SZ   = 4;
constexpr int L_DIM  = 4096;
constexpr int LIMIT  = 256;

__global__ __launch_bounds__(256) void band_gather_kernel(
    const float* __restrict__ x, float* __restrict__ out) {
    const int t = blockIdx.x * blockDim.x + threadIdx.x;
    // t in [0, B*L*(LIMIT/4)) = [0, 1048576)
    const int j4 = (t & 63) << 2;          // output col group: 0..252, step 4
    const int i  = (t >> 6) & (L_DIM - 1); // row
    const int b  = t >> 18;                // batch

    const size_t row_off = ((size_t)b * L_DIM + i);
    const float* __restrict__ xrow = x + row_off * L_DIM;

    const int base = i + j4;
    const int lim  = L_DIM - i;            // valid while j < lim

    float4 v;
    v.x = (j4 + 0 < lim) ? xrow[base + 0] : 0.0f;
    v.y = (j4 + 1 < lim) ? xrow[base + 1] : 0.0f;
    v.z = (j4 + 2 < lim) ? xrow[base + 2] : 0.0f;
    v.w = (j4 + 3 < lim) ? xrow[base + 3] : 0.0f;

    float4* __restrict__ orow = (float4*)(out + row_off * LIMIT);
    orow[j4 >> 2] = v;
}

extern "C" void kernel_launch(void* const* d_in, const int* in_sizes, int n_in,
                              void* d_out, int out_size, void* d_ws, size_t ws_size,
                              hipStream_t stream) {
    const float* x = (const float*)d_in[0];
    float* out = (float*)d_out;

    const int total_threads = B_SZ * L_DIM * (LIMIT / 4); // 1,048,576
    const int block = 256;
    const int grid = total_threads / block;               // 4096
    band_gather_kernel<<<grid, block, 0, stream>>>(x, out);
}

// Round 2
// 297.455 us; speedup vs baseline: 1.0016x; 1.0016x over previous
//
#include <hip/hip_runtime.h>

// out[b, i, j] = x[b, i, i+j] if i+j < L else 0
// B=4, L=4096, LIMIT=256. Pure memory-bound band gather.
// One thread per float4 of output. Fast path: single misaligned (4B-aligned)
// global_load_dwordx4 when all 4 elements are in-band AND in-bounds
// (i + j4 + 4 <= L). Slow path (last 255 rows per batch only): predicated
// scalar loads that never read past x[b, i, L-1].

constexpr int B_SZ   = 4;
constexpr int L_DIM  = 4096;
constexpr int LIMIT  = 256;

// 16B vector with 4B alignment: gfx950 handles misaligned global_load_dwordx4.
typedef float float4u __attribute__((ext_vector_type(4), aligned(4)));
typedef float float4a __attribute__((ext_vector_type(4), aligned(16)));

__global__ __launch_bounds__(256) void band_gather_kernel(
    const float* __restrict__ x, float* __restrict__ out) {
    const int t = blockIdx.x * blockDim.x + threadIdx.x;
    // t in [0, B*L*(LIMIT/4)) = [0, 1048576)
    const int j4 = (t & 63) << 2;          // output col group: 0..252, step 4
    const int i  = (t >> 6) & (L_DIM - 1); // row
    const int b  = t >> 18;                // batch

    const size_t row = (size_t)b * L_DIM + i;
    const float* __restrict__ xrow = x + row * L_DIM;

    const int base = i + j4;

    float4u v;
    if (base + 4 <= L_DIM) {
        // all 4 elements valid; single (possibly misaligned) 16B load
        v = *(const float4u*)(xrow + base);
    } else {
        const int lim = L_DIM - i;         // valid while j < lim
        v.x = (j4 + 0 < lim) ? xrow[base + 0] : 0.0f;
        v.y = (j4 + 1 < lim) ? xrow[base + 1] : 0.0f;
        v.z = (j4 + 2 < lim) ? xrow[base + 2] : 0.0f;
        v.w = (j4 + 3 < lim) ? xrow[base + 3] : 0.0f;
    }

    float4a* __restrict__ orow = (float4a*)(out + row * LIMIT);
    orow[j4 >> 2] = (float4a)v;
}

extern "C" void kernel_launch(void* const* d_in, const int* in_sizes, int n_in,
                              void* d_out, int out_size, void* d_ws, size_t ws_size,
                              hipStream_t stream) {
    const float* x = (const float*)d_in[0];
    float* out = (float*)d_out;

    const int total_threads = B_SZ * L_DIM * (LIMIT / 4); // 1,048,576
    const int block = 256;
    const int grid = total_threads / block;               // 4096
    band_gather_kernel<<<grid, block, 0, stream>>>(x, out);
}